// Round 17
// baseline (241.318 us; speedup 1.0000x reference)
//
#include <hip/hip_runtime.h>

constexpr int G = 64;
constexpr int C = 16;
constexpr int NBATCH = 4;
constexpr int HID = 96;
constexpr int G3 = G * G * G; // 262144 = 2^18

typedef _Float16 h2    __attribute__((ext_vector_type(2)));
typedef _Float16 f16x4 __attribute__((ext_vector_type(4)));
typedef _Float16 f16x8 __attribute__((ext_vector_type(8)));
typedef float    f32x4 __attribute__((ext_vector_type(4)));

__device__ __forceinline__ f32x4 mfma16(f16x8 a, f16x8 b, f32x4 c) {
    return __builtin_amdgcn_mfma_f32_16x16x32_f16(a, b, c, 0, 0, 0);
}

#if __has_builtin(__builtin_amdgcn_global_load_lds)
#define HAS_GLL 1
__device__ __forceinline__ void gload_lds(const float* g, float* l) {
    __builtin_amdgcn_global_load_lds(
        (const __attribute__((address_space(1))) void*)g,
        (__attribute__((address_space(3))) void*)l, 4, 0, 0);
}
#else
#define HAS_GLL 0
#endif

// ---------------------------------------------------------------------------
// Pass 0: pack W1 (96x64) and W2 (16x96) into MFMA A-fragment order (f16).
// A-frag for mfma_f32_16x16x32_f16: lane l holds A[row = l%16][k = (l/16)*8+j],
// j=0..7 (16B contiguous per lane). (Layout verified by R11: absmax 0.03125.)
// ---------------------------------------------------------------------------
__global__ __launch_bounds__(256)
void nca_packw(const float* __restrict__ w1, const float* __restrict__ w2,
               _Float16* __restrict__ a1p, _Float16* __restrict__ a2p)
{
    const int i = blockIdx.x * 256 + threadIdx.x; // 0..6143
    {
        const int j = i & 7, lane = (i >> 3) & 63, f = i >> 9; // f = mt*2+kt
        const int mt = f >> 1, kt = f & 1;
        const int y = mt * 16 + (lane & 15);
        const int x = kt * 32 + ((lane >> 4) << 3) + j;
        a1p[i] = (_Float16)w1[y * 64 + x];
    }
    if (i < 3 * 512) {
        const int j = i & 7, lane = (i >> 3) & 63, kt2 = i >> 9;
        const int c = lane & 15;
        const int y = kt2 * 32 + ((lane >> 4) << 3) + j;
        a2p[i] = (_Float16)w2[c * HID + y];
    }
}

// ---------------------------------------------------------------------------
// Pass 1: perception + MFMA MLP + pre-alive fold-in.
//
// R17: recover the 64-VGPR tier (R15/R16 A-B proved the wave-slot boundary
// is exactly 64: VGPR 64->37.9% occ, 84->28.9%) while keeping R16's ideal
// traffic (FETCH 180 MB):
//  - ctrf[16] leaves registers: the 16 identity features (already f16 in
//    pp[0..7]) are parked in an 8 KB LDS sidecar at X-write time and read
//    back (own 32 B) in the epilogue. s0 passthrough is f16-rounded:
//    err <= 2.5e-3 << 0.031 GEMM-path absmax.
//  - LDS trimmed to exactly 40960 B -> 4 blocks/CU: X-panel XROW 144->128
//    with XOR swizzle (q*16)^((row&7)<<4) on both write and bfr read (same
//    involution -> bank cost = b128-inherent only); staging in 4 groups of
//    4 channels (2 x 9.6 KB buffers aliasing the panel region, issue-next-
//    before-compute overlap preserved).
//  - __launch_bounds__(256,4) pins the 64 cap (R15: natural live set = 64).
//  - grid 2048 / (256 CU x 4 blocks) = 2 exact rounds, no tail.
// Invariant: WRITE_SIZE 69632 KB (spill detector).
// ---------------------------------------------------------------------------
constexpr int HALO_N = 600;          // 10*10*6, linear per channel
constexpr int GBUF_F = 4 * HALO_N;   // 2400 floats per 4-channel buffer
constexpr int XROW   = 128;          // X-panel row stride (bytes), swizzled
constexpr int XWAVE  = 64 * XROW;    // 8192 B per wave
constexpr int HROW   = 80;           // H / delta-transpose row stride (bytes)
constexpr int SIDE_OFF = 4 * XWAVE;  // 32768: ident sidecar (256 x 32 B)
constexpr int SMEM_B = SIDE_OFF + 256 * 32; // 40960 B total

__global__ __launch_bounds__(256, 4)
void nca_update(const float* __restrict__ state, const float* __restrict__ rand_u,
                const _Float16* __restrict__ a1p, const float* __restrict__ b1,
                const _Float16* __restrict__ a2p,
                float* __restrict__ out, float* __restrict__ acopy)
{
    __shared__ __align__(16) char smem[SMEM_B];
    float* bufA = (float*)smem;          // 9600 B
    float* bufB = bufA + GBUF_F;         // 9600 B; both alias panel region

    const int tid = threadIdx.x;
    const int bid = blockIdx.x;
    const int bx = bid & 7, by = (bid >> 3) & 7, bz = (bid >> 6) & 15, n = bid >> 10;
    const int x0 = bx * 8, y0 = by * 8, z0 = bz * 4;
    const float* sb = state + (size_t)n * C * G3;

    // --- halo source offsets, linear j-order (identical every channel) ---
    int vo0, vo1, vo2;
    {
        const int j = tid;
        const int lx = j % 10, t = j / 10, ly = t % 10, lz = t / 10;
        vo0 = min(max(z0 + lz - 1, 0), G - 1) * (G * G)
            + min(max(y0 + ly - 1, 0), G - 1) * G
            + min(max(x0 + lx - 1, 0), G - 1);
    }
    {
        const int j = tid + 256;
        const int lx = j % 10, t = j / 10, ly = t % 10, lz = t / 10;
        vo1 = min(max(z0 + lz - 1, 0), G - 1) * (G * G)
            + min(max(y0 + ly - 1, 0), G - 1) * G
            + min(max(x0 + lx - 1, 0), G - 1);
    }
    const bool act2 = (tid + 512 < HALO_N);
    {
        const int j = min(tid + 512, HALO_N - 1);
        const int lx = j % 10, t = j / 10, ly = t % 10, lz = t / 10;
        vo2 = min(max(z0 + lz - 1, 0), G - 1) * (G * G)
            + min(max(y0 + ly - 1, 0), G - 1) * G
            + min(max(x0 + lx - 1, 0), G - 1);
    }
    const int wbase = tid & ~63; // wave-uniform LDS slot base

    // Own voxel.
    const int lxl = (tid & 7) + 1, lyl = ((tid >> 3) & 7) + 1, lzl = (tid >> 6) + 1;
    const int cbase = (lzl - 1) * 100 + (lyl - 1) * 10 + (lxl - 1);
    const size_t vofs = (size_t)(z0 + lzl - 1) * (G * G)
                      + (size_t)(y0 + lyl - 1) * G + (x0 + lxl - 1);
    const float ru = rand_u[(size_t)n * G3 + vofs]; // own rand, issued early

    // Packed perception features (h2 pp[j] = features 2j,2j+1; x = k*16+c).
    h2 pp[32];
    float pf0 = 0.f, pf1 = 0.f, pf2 = 0.f, pf3 = 0.f; // even-channel carry
    float amax = -3.0e38f;

    // --- 4-group staging pipeline: [stage g+1][stencil g][barrier] ---
#if HAS_GLL
#define STAGE(gi, dst)                                                       \
    {                                                                        \
        const float* s4 = sb + (size_t)((gi) * 4) * G3;                      \
        _Pragma("unroll")                                                    \
        for (int c = 0; c < 4; ++c) {                                        \
            const float* gc = s4 + (size_t)c * G3;                           \
            gload_lds(gc + vo0, (dst) + c * HALO_N + wbase);                 \
            gload_lds(gc + vo1, (dst) + c * HALO_N + 256 + wbase);           \
            if (act2) gload_lds(gc + vo2, (dst) + c * HALO_N + 512 + wbase); \
        }                                                                    \
    }
#else
#define STAGE(gi, dst)                                                       \
    {                                                                        \
        const float* s4 = sb + (size_t)((gi) * 4) * G3;                      \
        _Pragma("unroll")                                                    \
        for (int c = 0; c < 4; ++c) {                                        \
            const float* gc = s4 + (size_t)c * G3;                           \
            (dst)[c * HALO_N + tid] = gc[vo0];                               \
            (dst)[c * HALO_N + 256 + tid] = gc[vo1];                         \
            if (act2) (dst)[c * HALO_N + 512 + tid] = gc[vo2];               \
        }                                                                    \
    }
#endif

    STAGE(0, bufA);
    __syncthreads(); // group 0 staged

#pragma unroll
    for (int g = 0; g < 4; ++g) {
        if (g < 3) { // issue next group into the other buffer (latency hides
                     // under this group's stencil; drained by the barrier)
            float* nb = (g & 1) ? bufA : bufB;
            STAGE(g + 1, nb);
        }
        const float* bb = (g & 1) ? bufB : bufA;

#pragma unroll
        for (int c = 0; c < 4; ++c) {
            const int cg = g * 4 + c;
            const float* buf = bb + c * HALO_N;
            float P0 = 0.f, P2 = 0.f, U0 = 0.f, U2 = 0.f, V0 = 0.f, V2 = 0.f;
            float ctr = 0.f, mx = -3.0e38f;
#pragma unroll
            for (int dz = 0; dz < 3; ++dz) {
                const float gzw = (dz == 1) ? 2.f : 1.f;
#pragma unroll
                for (int dy = 0; dy < 3; ++dy) {
                    const float gyw = (dy == 1) ? 2.f : 1.f;
                    const float* r = buf + cbase + dz * 100 + dy * 10;
                    const float a0 = r[0], a1 = r[1], a2 = r[2];
                    const float rs = a0 + 2.f * a1 + a2;
                    if (dz == 0) P0 += gyw * rs;
                    if (dz == 2) P2 += gyw * rs;
                    if (dy == 0) U0 += gzw * rs;
                    if (dy == 2) U2 += gzw * rs;
                    V0 += gzw * gyw * a0;
                    V2 += gzw * gyw * a2;
                    if (dz == 1 && dy == 1) ctr = a1;
                    if (cg == 3) mx = fmaxf(mx, fmaxf(fmaxf(a0, a1), a2));
                }
            }
            if (cg == 3) amax = mx;

            const float f0 = ctr;
            const float f1 = (P0 - P2) * 0.0625f;
            const float f2 = (U0 - U2) * 0.0625f;
            const float f3 = (V0 - V2) * 0.0625f;

            if (cg & 1) {
                const int j = cg >> 1;
                h2 v;
                v.x = (_Float16)pf0; v.y = (_Float16)f0; pp[j]      = v;
                v.x = (_Float16)pf1; v.y = (_Float16)f1; pp[8 + j]  = v;
                v.x = (_Float16)pf2; v.y = (_Float16)f2; pp[16 + j] = v;
                v.x = (_Float16)pf3; v.y = (_Float16)f3; pp[24 + j] = v;
            } else {
                pf0 = f0; pf1 = f1; pf2 = f2; pf3 = f3;
            }
        }
        __syncthreads(); // next group staged + WAR guard on bb / final: panels
    }
#undef STAGE

    const float pre = (amax > 0.1f) ? 1.f : 0.f; // own voxel

    // =================== MFMA MLP (wave-private) ===================
    const int lane = tid & 63;
    const int w    = tid >> 6;       // wave = z-slice
    const int l15  = lane & 15;
    const int lg   = lane >> 4;      // lane group 0..3
    char* xw   = smem + w * XWAVE;
    char* side = smem + SIDE_OFF + tid * 32;

    // --- park the 16 identity features (f16) in the sidecar ---
    {
        uint4 ia, ib;
        ia.x = __builtin_bit_cast(unsigned, pp[0]);
        ia.y = __builtin_bit_cast(unsigned, pp[1]);
        ia.z = __builtin_bit_cast(unsigned, pp[2]);
        ia.w = __builtin_bit_cast(unsigned, pp[3]);
        ib.x = __builtin_bit_cast(unsigned, pp[4]);
        ib.y = __builtin_bit_cast(unsigned, pp[5]);
        ib.z = __builtin_bit_cast(unsigned, pp[6]);
        ib.w = __builtin_bit_cast(unsigned, pp[7]);
        *(uint4*)(side) = ia;
        *(uint4*)(side + 16) = ib;
    }

    // --- write X-panel: row v = lane, 64 f16, XOR-swizzled 16B slots ---
#pragma unroll
    for (int q = 0; q < 8; ++q) {
        uint4 t;
        t.x = __builtin_bit_cast(unsigned, pp[4 * q]);
        t.y = __builtin_bit_cast(unsigned, pp[4 * q + 1]);
        t.z = __builtin_bit_cast(unsigned, pp[4 * q + 2]);
        t.w = __builtin_bit_cast(unsigned, pp[4 * q + 3]);
        *(uint4*)(xw + lane * XROW + ((q * 16) ^ ((lane & 7) << 4))) = t;
    }

    // --- load B1 fragments (X^T): B[k][v], lane: k=lg*8+j, v=nt*16+l15 ---
    f16x8 bfr[8]; // [kt*4 + nt]
#pragma unroll
    for (int kt = 0; kt < 2; ++kt)
#pragma unroll
        for (int nt = 0; nt < 4; ++nt) {
            const int v = nt * 16 + l15;
            bfr[kt * 4 + nt] = *(const f16x8*)(
                xw + v * XROW + ((kt * 64 + lg * 16) ^ ((v & 7) << 4)));
        }

    const f16x8* a1 = ((const f16x8*)a1p) + lane;
    const f16x8* a2 = ((const f16x8*)a2p) + lane;

    f32x4 acc2[4];
#pragma unroll
    for (int nt = 0; nt < 4; ++nt) acc2[nt] = (f32x4){0.f, 0.f, 0.f, 0.f};

    // --- interleaved GEMM1/GEMM2 per 32-row hidden block ---
    // (DS ops are per-wave in-order: H writes over the dead X region are
    //  safe after the bfr reads above.)
#pragma unroll 1
    for (int kt2 = 0; kt2 < 3; ++kt2) {
#pragma unroll
        for (int mtsub = 0; mtsub < 2; ++mtsub) {
            const int mt = kt2 * 2 + mtsub;
            const f16x8 a_0 = a1[(mt * 2 + 0) * 64];
            const f16x8 a_1 = a1[(mt * 2 + 1) * 64];
            const f32x4 bias = *(const f32x4*)(b1 + mt * 16 + lg * 4);
#pragma unroll
            for (int nt = 0; nt < 4; ++nt) {
                f32x4 acc = (f32x4){0.f, 0.f, 0.f, 0.f};
                acc = mfma16(a_0, bfr[nt],     acc);
                acc = mfma16(a_1, bfr[4 + nt], acc);
                f16x4 hv;
                hv[0] = (_Float16)fmaxf(acc[0] + bias[0], 0.f);
                hv[1] = (_Float16)fmaxf(acc[1] + bias[1], 0.f);
                hv[2] = (_Float16)fmaxf(acc[2] + bias[2], 0.f);
                hv[3] = (_Float16)fmaxf(acc[3] + bias[3], 0.f);
                *(f16x4*)(xw + (nt * 16 + l15) * HROW + mtsub * 32 + lg * 8) = hv;
            }
        }
        const f16x8 a2f = a2[kt2 * 64];
#pragma unroll
        for (int nt = 0; nt < 4; ++nt) {
            const f16x8 b2 = *(const f16x8*)(xw + (nt * 16 + l15) * HROW + lg * 16);
            acc2[nt] = mfma16(a2f, b2, acc2[nt]);
        }
    }

    // --- delta transpose through the (now dead) H panel: row = voxel ---
#pragma unroll
    for (int nt = 0; nt < 4; ++nt) {
        *(f32x4*)(xw + (nt * 16 + l15) * HROW + lg * 16) = acc2[nt];
    }

    // --- epilogue: own voxel, all 16 channels; s0 from the ident sidecar ---
    const float m = (ru < 0.5f) ? 1.f : 0.f;
    const uint4 ia = *(const uint4*)(side);
    const uint4 ib = *(const uint4*)(side + 16);
    float s0v[16];
    {
        const unsigned wds[8] = {ia.x, ia.y, ia.z, ia.w, ib.x, ib.y, ib.z, ib.w};
#pragma unroll
        for (int j = 0; j < 8; ++j) {
            const h2 p = __builtin_bit_cast(h2, wds[j]);
            s0v[2 * j]     = (float)p.x;
            s0v[2 * j + 1] = (float)p.y;
        }
    }
    float* ob = out + (size_t)n * C * G3;
    float* ac = acopy + (size_t)n * G3;
#pragma unroll
    for (int q = 0; q < 4; ++q) {
        const f32x4 dv = *(const f32x4*)(xw + lane * HROW + q * 16);
#pragma unroll
        for (int r = 0; r < 4; ++r) {
            const int c = q * 4 + r;
            const float nv = fmaf(dv[r], m, s0v[c]);
            if (c == 3) ac[vofs] = nv; // UNMASKED new alpha
            ob[(size_t)c * G3 + vofs] = nv * pre;
        }
    }
}

// ---------------------------------------------------------------------------
// Pass 2 (fused): post-alive pooling on the unmasked new alpha (acopy) ->
// zero out dead voxels only. Alive voxels (overwhelming majority) touch no
// out traffic: multiplying by 1 is a no-op. Bit-exact vs out *= mask.
// ---------------------------------------------------------------------------
__global__ __launch_bounds__(256)
void nca_post(const float* __restrict__ acopy, float* __restrict__ out)
{
    const int idx = blockIdx.x * 256 + threadIdx.x; // over NBATCH*G3
    const int n = idx >> 18;
    const int v = idx & (G3 - 1);
    const int x = v & 63, y = (v >> 6) & 63, z = v >> 12;
    const float* ab = acopy + (size_t)n * G3;
    float mx = -3.0e38f;
#pragma unroll
    for (int dz = -1; dz <= 1; ++dz) {
        const int zz = min(max(z + dz, 0), G - 1);
#pragma unroll
        for (int dy = -1; dy <= 1; ++dy) {
            const int yy = min(max(y + dy, 0), G - 1);
            const int xm = max(x - 1, 0), xp = min(x + 1, G - 1);
            const float* row = ab + (size_t)zz * (G * G) + (size_t)yy * G;
            mx = fmaxf(mx, fmaxf(fmaxf(row[xm], row[x]), row[xp]));
        }
    }
    if (mx > 0.1f) return; // alive: out already holds new_state * pre
    float* ob = out + (size_t)n * C * G3 + v;
#pragma unroll
    for (int c = 0; c < C; ++c) ob[(size_t)c * G3] = 0.f;
}

extern "C" void kernel_launch(void* const* d_in, const int* in_sizes, int n_in,
                              void* d_out, int out_size, void* d_ws, size_t ws_size,
                              hipStream_t stream)
{
    const float* state  = (const float*)d_in[0];
    const float* rand_u = (const float*)d_in[1];
    const float* w1     = (const float*)d_in[2];
    const float* b1     = (const float*)d_in[3];
    const float* w2     = (const float*)d_in[4];
    float* out  = (float*)d_out;

    // Workspace: [0,12KB) a1p, [12KB,15KB) a2p, [16KB, 16KB+4MiB) acopy.
    _Float16* a1p  = (_Float16*)d_ws;
    _Float16* a2p  = (_Float16*)((char*)d_ws + 12 * 1024);
    float*    acop = (float*)((char*)d_ws + 16 * 1024);

    nca_packw <<<24, 256, 0, stream>>>(w1, w2, a1p, a2p);
    nca_update<<<NBATCH * 8 * 8 * 16, 256, 0, stream>>>(state, rand_u, a1p, b1, a2p, out, acop);
    nca_post  <<<(NBATCH * G3) / 256, 256, 0, stream>>>(acop, out);
}

// Round 18
// 125.718 us; speedup vs baseline: 1.9195x; 1.9195x over previous
//
#include <hip/hip_runtime.h>

constexpr int G = 64;
constexpr int C = 16;
constexpr int NBATCH = 4;
constexpr int HID = 96;
constexpr int G3 = G * G * G; // 262144 = 2^18

typedef _Float16 h2    __attribute__((ext_vector_type(2)));
typedef _Float16 f16x4 __attribute__((ext_vector_type(4)));
typedef _Float16 f16x8 __attribute__((ext_vector_type(8)));
typedef float    f32x4 __attribute__((ext_vector_type(4)));

__device__ __forceinline__ f32x4 mfma16(f16x8 a, f16x8 b, f32x4 c) {
    return __builtin_amdgcn_mfma_f32_16x16x32_f16(a, b, c, 0, 0, 0);
}

#if __has_builtin(__builtin_amdgcn_global_load_lds)
#define HAS_GLL 1
__device__ __forceinline__ void gload_lds(const float* g, float* l) {
    __builtin_amdgcn_global_load_lds(
        (const __attribute__((address_space(1))) void*)g,
        (__attribute__((address_space(3))) void*)l, 4, 0, 0);
}
#else
#define HAS_GLL 0
#endif

// ---------------------------------------------------------------------------
// Pass 0: pack W1 (96x64) and W2 (16x96) into MFMA A-fragment order (f16).
// A-frag for mfma_f32_16x16x32_f16: lane l holds A[row = l%16][k = (l/16)*8+j],
// j=0..7 (16B contiguous per lane). (Layout verified by R11: absmax 0.03125.)
// ---------------------------------------------------------------------------
__global__ __launch_bounds__(256)
void nca_packw(const float* __restrict__ w1, const float* __restrict__ w2,
               _Float16* __restrict__ a1p, _Float16* __restrict__ a2p)
{
    const int i = blockIdx.x * 256 + threadIdx.x; // 0..6143
    {
        const int j = i & 7, lane = (i >> 3) & 63, f = i >> 9; // f = mt*2+kt
        const int mt = f >> 1, kt = f & 1;
        const int y = mt * 16 + (lane & 15);
        const int x = kt * 32 + ((lane >> 4) << 3) + j;
        a1p[i] = (_Float16)w1[y * 64 + x];
    }
    if (i < 3 * 512) {
        const int j = i & 7, lane = (i >> 3) & 63, kt2 = i >> 9;
        const int c = lane & 15;
        const int y = kt2 * 32 + ((lane >> 4) << 3) + j;
        a2p[i] = (_Float16)w2[c * HID + y];
    }
}

// ---------------------------------------------------------------------------
// Pass 1: perception + MFMA MLP + pre-alive fold-in.
//
// R18 = R16 minus ctrf[16], plus the 64-VGPR tier.
// R17's lesson: the (256,4) cap spills when the live set grows (4-group
// STAGE + sidecar + swizzle pushed it past 64 -> 420 MB scratch, 241 us).
// But R17 DID validate f16-rounded s0 numerically (absmax 0.03125 passed).
// The minimal form: in the voxel-major epilogue each thread finishes its
// OWN voxel, and its own pp[0..7] (8 VGPRs) ARE that voxel's 16 identity
// features == s0 (f16). So: drop ctrf entirely, decode s0 from pp at the
// end. GEMM live set ~= bfr(16)+acc2(16)+pp0-7(8)+addr(~15) ~= 55 < 64
// (R15 fit 64 with the identical stencil phase). Everything else is
// R16-verbatim: 2-group async staging, XROW 144, LDS 38400 (4 blocks/CU
// possible), voxel-major epilogue via H-panel transpose.
// Invariant: WRITE_SIZE 69632 KB (spill detector; if fired, revert cap).
// ---------------------------------------------------------------------------
constexpr int HALO_N = 600;       // 10*10*6, linear per channel
constexpr int BUF_F  = 8 * HALO_N;// 4800 floats per group buffer
constexpr int XROW = 144;         // X-panel row stride (bytes)
constexpr int HROW = 80;          // H / delta-transpose row stride (bytes)
constexpr int XWAVE = 64 * XROW;  // 9216 B per wave

__global__ __launch_bounds__(256, 4)
void nca_update(const float* __restrict__ state, const float* __restrict__ rand_u,
                const _Float16* __restrict__ a1p, const float* __restrict__ b1,
                const _Float16* __restrict__ a2p,
                float* __restrict__ out, float* __restrict__ acopy)
{
    // 2 x 4800 floats (stencil) = 38400 B; GEMM panels (4 x 9216 = 36864 B)
    // alias the same region after the post-stencil barrier.
    __shared__ __align__(16) char smem[2 * BUF_F * 4];
    float* buf0 = (float*)smem;
    float* buf1 = buf0 + BUF_F;

    const int tid = threadIdx.x;
    const int bid = blockIdx.x;
    const int bx = bid & 7, by = (bid >> 3) & 7, bz = (bid >> 6) & 15, n = bid >> 10;
    const int x0 = bx * 8, y0 = by * 8, z0 = bz * 4;
    const float* sb = state + (size_t)n * C * G3;

    // --- halo source offsets, linear j-order (identical every channel) ---
    int vo0, vo1, vo2;
    {
        const int j = tid;
        const int lx = j % 10, t = j / 10, ly = t % 10, lz = t / 10;
        vo0 = min(max(z0 + lz - 1, 0), G - 1) * (G * G)
            + min(max(y0 + ly - 1, 0), G - 1) * G
            + min(max(x0 + lx - 1, 0), G - 1);
    }
    {
        const int j = tid + 256;
        const int lx = j % 10, t = j / 10, ly = t % 10, lz = t / 10;
        vo1 = min(max(z0 + lz - 1, 0), G - 1) * (G * G)
            + min(max(y0 + ly - 1, 0), G - 1) * G
            + min(max(x0 + lx - 1, 0), G - 1);
    }
    const bool act2 = (tid + 512 < HALO_N);
    {
        const int j = min(tid + 512, HALO_N - 1);
        const int lx = j % 10, t = j / 10, ly = t % 10, lz = t / 10;
        vo2 = min(max(z0 + lz - 1, 0), G - 1) * (G * G)
            + min(max(y0 + ly - 1, 0), G - 1) * G
            + min(max(x0 + lx - 1, 0), G - 1);
    }
    const int wbase = tid & ~63; // wave-uniform LDS slot base

    // Own voxel (== lane's voxel of wave's z-slice).
    const int lxl = (tid & 7) + 1, lyl = ((tid >> 3) & 7) + 1, lzl = (tid >> 6) + 1;
    const int cbase = (lzl - 1) * 100 + (lyl - 1) * 10 + (lxl - 1);
    const size_t vofs = (size_t)(z0 + lzl - 1) * (G * G)
                      + (size_t)(y0 + lyl - 1) * G + (x0 + lxl - 1);
    const float ru = rand_u[(size_t)n * G3 + vofs]; // own rand, issued early

#if HAS_GLL
    // --- issue group 0 (ch 0-7) -> buf0, async, zero VGPR ---
#pragma unroll
    for (int c = 0; c < 8; ++c) {
        const float* gc = sb + (size_t)c * G3;
        gload_lds(gc + vo0, buf0 + c * HALO_N + wbase);
        gload_lds(gc + vo1, buf0 + c * HALO_N + 256 + wbase);
        if (act2) gload_lds(gc + vo2, buf0 + c * HALO_N + 512 + wbase);
    }
    __syncthreads(); // drains vmcnt -> buf0 complete

    // --- issue group 1 (ch 8-15) -> buf1; latency hides under stencil g0 ---
#pragma unroll
    for (int c = 0; c < 8; ++c) {
        const float* gc = sb + (size_t)(8 + c) * G3;
        gload_lds(gc + vo0, buf1 + c * HALO_N + wbase);
        gload_lds(gc + vo1, buf1 + c * HALO_N + 256 + wbase);
        if (act2) gload_lds(gc + vo2, buf1 + c * HALO_N + 512 + wbase);
    }
#else
    // Fallback: synchronous staging (correct, no overlap).
#pragma unroll
    for (int c = 0; c < 8; ++c) {
        const float* gc = sb + (size_t)c * G3;
        buf0[c * HALO_N + tid] = gc[vo0];
        buf0[c * HALO_N + 256 + tid] = gc[vo1];
        if (act2) buf0[c * HALO_N + 512 + tid] = gc[vo2];
    }
    __syncthreads();
#pragma unroll
    for (int c = 0; c < 8; ++c) {
        const float* gc = sb + (size_t)(8 + c) * G3;
        buf1[c * HALO_N + tid] = gc[vo0];
        buf1[c * HALO_N + 256 + tid] = gc[vo1];
        if (act2) buf1[c * HALO_N + 512 + tid] = gc[vo2];
    }
#endif

    // Packed perception features (h2 pp[j] = features 2j,2j+1; x = k*16+c).
    // pp[0..7] (identity, k=0) double as the exact-f16 s0 for the epilogue.
    h2 pp[32];
    float pf0 = 0.f, pf1 = 0.f, pf2 = 0.f, pf3 = 0.f; // even-channel carry
    float amax = -3.0e38f;

#pragma unroll
    for (int g = 0; g < 2; ++g) {
        const float* bb = g ? buf1 : buf0;
        if (g) __syncthreads(); // drains buf1's loads (issued pre-stencil-g0)

#pragma unroll
        for (int c = 0; c < 8; ++c) {
            const int cg = g * 8 + c;
            const float* buf = bb + c * HALO_N;
            float P0 = 0.f, P2 = 0.f, U0 = 0.f, U2 = 0.f, V0 = 0.f, V2 = 0.f;
            float ctr = 0.f, mx = -3.0e38f;
#pragma unroll
            for (int dz = 0; dz < 3; ++dz) {
                const float gzw = (dz == 1) ? 2.f : 1.f;
#pragma unroll
                for (int dy = 0; dy < 3; ++dy) {
                    const float gyw = (dy == 1) ? 2.f : 1.f;
                    const float* r = buf + cbase + dz * 100 + dy * 10;
                    const float a0 = r[0], a1 = r[1], a2 = r[2];
                    const float rs = a0 + 2.f * a1 + a2;
                    if (dz == 0) P0 += gyw * rs;
                    if (dz == 2) P2 += gyw * rs;
                    if (dy == 0) U0 += gzw * rs;
                    if (dy == 2) U2 += gzw * rs;
                    V0 += gzw * gyw * a0;
                    V2 += gzw * gyw * a2;
                    if (dz == 1 && dy == 1) ctr = a1;
                    if (cg == 3) mx = fmaxf(mx, fmaxf(fmaxf(a0, a1), a2));
                }
            }
            if (cg == 3) amax = mx;

            const float f0 = ctr;
            const float f1 = (P0 - P2) * 0.0625f;
            const float f2 = (U0 - U2) * 0.0625f;
            const float f3 = (V0 - V2) * 0.0625f;

            if (cg & 1) {
                const int j = cg >> 1;
                h2 v;
                v.x = (_Float16)pf0; v.y = (_Float16)f0; pp[j]      = v;
                v.x = (_Float16)pf1; v.y = (_Float16)f1; pp[8 + j]  = v;
                v.x = (_Float16)pf2; v.y = (_Float16)f2; pp[16 + j] = v;
                v.x = (_Float16)pf3; v.y = (_Float16)f3; pp[24 + j] = v;
            } else {
                pf0 = f0; pf1 = f1; pf2 = f2; pf3 = f3;
            }
        }
    }

    // All waves finished reading the buffers; X/H panels may overwrite.
    __syncthreads();

    const float pre = (amax > 0.1f) ? 1.f : 0.f; // own voxel

    // =================== MFMA MLP (wave-private) ===================
    const int lane = tid & 63;
    const int w    = tid >> 6;       // wave = z-slice
    const int l15  = lane & 15;
    const int lg   = lane >> 4;      // lane group 0..3
    char* xw = smem + w * XWAVE;

    // --- write X-panel: row v = lane (this thread's voxel), 64 f16 ---
#pragma unroll
    for (int q = 0; q < 8; ++q) {
        uint4 t;
        t.x = __builtin_bit_cast(unsigned, pp[4 * q]);
        t.y = __builtin_bit_cast(unsigned, pp[4 * q + 1]);
        t.z = __builtin_bit_cast(unsigned, pp[4 * q + 2]);
        t.w = __builtin_bit_cast(unsigned, pp[4 * q + 3]);
        *(uint4*)(xw + lane * XROW + q * 16) = t;
    }

    // --- load B1 fragments (X^T): B[k][v], lane: k=lg*8+j, v=nt*16+l15 ---
    f16x8 bfr[8]; // [kt*4 + nt]
#pragma unroll
    for (int kt = 0; kt < 2; ++kt)
#pragma unroll
        for (int nt = 0; nt < 4; ++nt)
            bfr[kt * 4 + nt] = *(const f16x8*)(xw + (nt * 16 + l15) * XROW + kt * 64 + lg * 16);

    const f16x8* a1 = ((const f16x8*)a1p) + lane;
    const f16x8* a2 = ((const f16x8*)a2p) + lane;

    f32x4 acc2[4];
#pragma unroll
    for (int nt = 0; nt < 4; ++nt) acc2[nt] = (f32x4){0.f, 0.f, 0.f, 0.f};

    // --- interleaved GEMM1/GEMM2 per 32-row hidden block ---
#pragma unroll 1
    for (int kt2 = 0; kt2 < 3; ++kt2) {
#pragma unroll
        for (int mtsub = 0; mtsub < 2; ++mtsub) {
            const int mt = kt2 * 2 + mtsub;
            const f16x8 a_0 = a1[(mt * 2 + 0) * 64];
            const f16x8 a_1 = a1[(mt * 2 + 1) * 64];
            const f32x4 bias = *(const f32x4*)(b1 + mt * 16 + lg * 4);
#pragma unroll
            for (int nt = 0; nt < 4; ++nt) {
                f32x4 acc = (f32x4){0.f, 0.f, 0.f, 0.f};
                acc = mfma16(a_0, bfr[nt],     acc);
                acc = mfma16(a_1, bfr[4 + nt], acc);
                f16x4 hv;
                hv[0] = (_Float16)fmaxf(acc[0] + bias[0], 0.f);
                hv[1] = (_Float16)fmaxf(acc[1] + bias[1], 0.f);
                hv[2] = (_Float16)fmaxf(acc[2] + bias[2], 0.f);
                hv[3] = (_Float16)fmaxf(acc[3] + bias[3], 0.f);
                *(f16x4*)(xw + (nt * 16 + l15) * HROW + mtsub * 32 + lg * 8) = hv;
            }
        }
        const f16x8 a2f = a2[kt2 * 64];
#pragma unroll
        for (int nt = 0; nt < 4; ++nt) {
            const f16x8 b2 = *(const f16x8*)(xw + (nt * 16 + l15) * HROW + lg * 16);
            acc2[nt] = mfma16(a2f, b2, acc2[nt]);
        }
    }

    // --- delta transpose through the (now dead) H panel: row = voxel ---
#pragma unroll
    for (int nt = 0; nt < 4; ++nt) {
        *(f32x4*)(xw + (nt * 16 + l15) * HROW + lg * 16) = acc2[nt];
    }

    // --- epilogue: own voxel, all 16 channels; s0 = own identity features
    //     (pp[0..7], f16 -- validated numerics, R17 absmax 0.03125) ---
    const float m = (ru < 0.5f) ? 1.f : 0.f;
    float s0v[16];
#pragma unroll
    for (int j = 0; j < 8; ++j) {
        s0v[2 * j]     = (float)pp[j].x;
        s0v[2 * j + 1] = (float)pp[j].y;
    }
    float* ob = out + (size_t)n * C * G3;
    float* ac = acopy + (size_t)n * G3;
#pragma unroll
    for (int q = 0; q < 4; ++q) {
        const f32x4 dv = *(const f32x4*)(xw + lane * HROW + q * 16);
#pragma unroll
        for (int r = 0; r < 4; ++r) {
            const int c = q * 4 + r;
            const float nv = fmaf(dv[r], m, s0v[c]);
            if (c == 3) ac[vofs] = nv; // UNMASKED new alpha
            ob[(size_t)c * G3 + vofs] = nv * pre;
        }
    }
}

// ---------------------------------------------------------------------------
// Pass 2 (fused): post-alive pooling on the unmasked new alpha (acopy) ->
// zero out dead voxels only. Alive voxels (overwhelming majority) touch no
// out traffic: multiplying by 1 is a no-op. Bit-exact vs out *= mask.
// ---------------------------------------------------------------------------
__global__ __launch_bounds__(256)
void nca_post(const float* __restrict__ acopy, float* __restrict__ out)
{
    const int idx = blockIdx.x * 256 + threadIdx.x; // over NBATCH*G3
    const int n = idx >> 18;
    const int v = idx & (G3 - 1);
    const int x = v & 63, y = (v >> 6) & 63, z = v >> 12;
    const float* ab = acopy + (size_t)n * G3;
    float mx = -3.0e38f;
#pragma unroll
    for (int dz = -1; dz <= 1; ++dz) {
        const int zz = min(max(z + dz, 0), G - 1);
#pragma unroll
        for (int dy = -1; dy <= 1; ++dy) {
            const int yy = min(max(y + dy, 0), G - 1);
            const int xm = max(x - 1, 0), xp = min(x + 1, G - 1);
            const float* row = ab + (size_t)zz * (G * G) + (size_t)yy * G;
            mx = fmaxf(mx, fmaxf(fmaxf(row[xm], row[x]), row[xp]));
        }
    }
    if (mx > 0.1f) return; // alive: out already holds new_state * pre
    float* ob = out + (size_t)n * C * G3 + v;
#pragma unroll
    for (int c = 0; c < C; ++c) ob[(size_t)c * G3] = 0.f;
}

extern "C" void kernel_launch(void* const* d_in, const int* in_sizes, int n_in,
                              void* d_out, int out_size, void* d_ws, size_t ws_size,
                              hipStream_t stream)
{
    const float* state  = (const float*)d_in[0];
    const float* rand_u = (const float*)d_in[1];
    const float* w1     = (const float*)d_in[2];
    const float* b1     = (const float*)d_in[3];
    const float* w2     = (const float*)d_in[4];
    float* out  = (float*)d_out;

    // Workspace: [0,12KB) a1p, [12KB,15KB) a2p, [16KB, 16KB+4MiB) acopy.
    _Float16* a1p  = (_Float16*)d_ws;
    _Float16* a2p  = (_Float16*)((char*)d_ws + 12 * 1024);
    float*    acop = (float*)((char*)d_ws + 16 * 1024);

    nca_packw <<<24, 256, 0, stream>>>(w1, w2, a1p, a2p);
    nca_update<<<NBATCH * 8 * 8 * 16, 256, 0, stream>>>(state, rand_u, a1p, b1, a2p, out, acop);
    nca_post  <<<(NBATCH * G3) / 256, 256, 0, stream>>>(acop, out);
}

// Round 19
// 120.262 us; speedup vs baseline: 2.0066x; 1.0454x over previous
//
#include <hip/hip_runtime.h>

constexpr int G = 64;
constexpr int C = 16;
constexpr int NBATCH = 4;
constexpr int HID = 96;
constexpr int G3 = G * G * G; // 262144 = 2^18

typedef _Float16 h2    __attribute__((ext_vector_type(2)));
typedef _Float16 f16x4 __attribute__((ext_vector_type(4)));
typedef _Float16 f16x8 __attribute__((ext_vector_type(8)));
typedef float    f32x4 __attribute__((ext_vector_type(4)));

__device__ __forceinline__ f32x4 mfma16(f16x8 a, f16x8 b, f32x4 c) {
    return __builtin_amdgcn_mfma_f32_16x16x32_f16(a, b, c, 0, 0, 0);
}

#if __has_builtin(__builtin_amdgcn_global_load_lds)
#define HAS_GLL 1
__device__ __forceinline__ void gload_lds(const float* g, float* l) {
    __builtin_amdgcn_global_load_lds(
        (const __attribute__((address_space(1))) void*)g,
        (__attribute__((address_space(3))) void*)l, 4, 0, 0);
}
#else
#define HAS_GLL 0
#endif

// ---------------------------------------------------------------------------
// Pass 0: pack W1 (96x64) and W2 (16x96) into MFMA A-fragment order (f16).
// A-frag for mfma_f32_16x16x32_f16: lane l holds A[row = l%16][k = (l/16)*8+j],
// j=0..7 (16B contiguous per lane). (Layout verified by R11: absmax 0.03125.)
// ---------------------------------------------------------------------------
__global__ __launch_bounds__(256)
void nca_packw(const float* __restrict__ w1, const float* __restrict__ w2,
               _Float16* __restrict__ a1p, _Float16* __restrict__ a2p)
{
    const int i = blockIdx.x * 256 + threadIdx.x; // 0..6143
    {
        const int j = i & 7, lane = (i >> 3) & 63, f = i >> 9; // f = mt*2+kt
        const int mt = f >> 1, kt = f & 1;
        const int y = mt * 16 + (lane & 15);
        const int x = kt * 32 + ((lane >> 4) << 3) + j;
        a1p[i] = (_Float16)w1[y * 64 + x];
    }
    if (i < 3 * 512) {
        const int j = i & 7, lane = (i >> 3) & 63, kt2 = i >> 9;
        const int c = lane & 15;
        const int y = kt2 * 32 + ((lane >> 4) << 3) + j;
        a2p[i] = (_Float16)w2[c * HID + y];
    }
}

// ---------------------------------------------------------------------------
// Pass 1: perception + MFMA MLP + pre-alive fold-in.
//
// R19 = R18 + the 8 identity regs parked in LDS during the GEMM.
// R18's WRITE_SIZE was 69632 + exactly 65536 KB = 8 floats/thread of
// scratch: the (256,4) 64-cap spilled precisely pp[0..7], which I kept
// live across the GEMM for the epilogue's s0. Fix at zero LDS cost: the
// per-wave panel region has a dead zone during the GEMM (H writes and the
// delta transpose stay < 5120 B; X bytes 5120..9216 are dead once bfr is
// loaded). Park pp[0..7] at xw+6144/+7168 + lane*16 (contiguous stride-16
// b128 = optimal LDS pattern) right after the bfr loads; read back in the
// epilogue. GEMM live set drops to ~55 regs = R15's proven 64-tier fit.
// DS ops are per-wave in-order, so no barrier is needed anywhere in this
// chain (same argument as H-over-X; used since R11).
// Invariant: WRITE_SIZE 69632 KB. If it still exceeds -> revert to R16.
// ---------------------------------------------------------------------------
constexpr int HALO_N = 600;       // 10*10*6, linear per channel
constexpr int BUF_F  = 8 * HALO_N;// 4800 floats per group buffer
constexpr int XROW = 144;         // X-panel row stride (bytes)
constexpr int HROW = 80;          // H / delta-transpose row stride (bytes)
constexpr int XWAVE = 64 * XROW;  // 9216 B per wave
constexpr int PARK0 = 6144;       // identity parking (per wave), 1 KiB
constexpr int PARK1 = 7168;       // second half, 1 KiB (ends at 8192 < 9216)

__global__ __launch_bounds__(256, 4)
void nca_update(const float* __restrict__ state, const float* __restrict__ rand_u,
                const _Float16* __restrict__ a1p, const float* __restrict__ b1,
                const _Float16* __restrict__ a2p,
                float* __restrict__ out, float* __restrict__ acopy)
{
    // 2 x 4800 floats (stencil) = 38400 B; GEMM panels (4 x 9216 = 36864 B)
    // alias the same region after the post-stencil barrier.
    __shared__ __align__(16) char smem[2 * BUF_F * 4];
    float* buf0 = (float*)smem;
    float* buf1 = buf0 + BUF_F;

    const int tid = threadIdx.x;
    const int bid = blockIdx.x;
    const int bx = bid & 7, by = (bid >> 3) & 7, bz = (bid >> 6) & 15, n = bid >> 10;
    const int x0 = bx * 8, y0 = by * 8, z0 = bz * 4;
    const float* sb = state + (size_t)n * C * G3;

    // --- halo source offsets, linear j-order (identical every channel) ---
    int vo0, vo1, vo2;
    {
        const int j = tid;
        const int lx = j % 10, t = j / 10, ly = t % 10, lz = t / 10;
        vo0 = min(max(z0 + lz - 1, 0), G - 1) * (G * G)
            + min(max(y0 + ly - 1, 0), G - 1) * G
            + min(max(x0 + lx - 1, 0), G - 1);
    }
    {
        const int j = tid + 256;
        const int lx = j % 10, t = j / 10, ly = t % 10, lz = t / 10;
        vo1 = min(max(z0 + lz - 1, 0), G - 1) * (G * G)
            + min(max(y0 + ly - 1, 0), G - 1) * G
            + min(max(x0 + lx - 1, 0), G - 1);
    }
    const bool act2 = (tid + 512 < HALO_N);
    {
        const int j = min(tid + 512, HALO_N - 1);
        const int lx = j % 10, t = j / 10, ly = t % 10, lz = t / 10;
        vo2 = min(max(z0 + lz - 1, 0), G - 1) * (G * G)
            + min(max(y0 + ly - 1, 0), G - 1) * G
            + min(max(x0 + lx - 1, 0), G - 1);
    }
    const int wbase = tid & ~63; // wave-uniform LDS slot base

    // Own voxel (== lane's voxel of wave's z-slice).
    const int lxl = (tid & 7) + 1, lyl = ((tid >> 3) & 7) + 1, lzl = (tid >> 6) + 1;
    const int cbase = (lzl - 1) * 100 + (lyl - 1) * 10 + (lxl - 1);
    const size_t vofs = (size_t)(z0 + lzl - 1) * (G * G)
                      + (size_t)(y0 + lyl - 1) * G + (x0 + lxl - 1);
    const float ru = rand_u[(size_t)n * G3 + vofs]; // own rand, issued early

#if HAS_GLL
    // --- issue group 0 (ch 0-7) -> buf0, async, zero VGPR ---
#pragma unroll
    for (int c = 0; c < 8; ++c) {
        const float* gc = sb + (size_t)c * G3;
        gload_lds(gc + vo0, buf0 + c * HALO_N + wbase);
        gload_lds(gc + vo1, buf0 + c * HALO_N + 256 + wbase);
        if (act2) gload_lds(gc + vo2, buf0 + c * HALO_N + 512 + wbase);
    }
    __syncthreads(); // drains vmcnt -> buf0 complete

    // --- issue group 1 (ch 8-15) -> buf1; latency hides under stencil g0 ---
#pragma unroll
    for (int c = 0; c < 8; ++c) {
        const float* gc = sb + (size_t)(8 + c) * G3;
        gload_lds(gc + vo0, buf1 + c * HALO_N + wbase);
        gload_lds(gc + vo1, buf1 + c * HALO_N + 256 + wbase);
        if (act2) gload_lds(gc + vo2, buf1 + c * HALO_N + 512 + wbase);
    }
#else
    // Fallback: synchronous staging (correct, no overlap).
#pragma unroll
    for (int c = 0; c < 8; ++c) {
        const float* gc = sb + (size_t)c * G3;
        buf0[c * HALO_N + tid] = gc[vo0];
        buf0[c * HALO_N + 256 + tid] = gc[vo1];
        if (act2) buf0[c * HALO_N + 512 + tid] = gc[vo2];
    }
    __syncthreads();
#pragma unroll
    for (int c = 0; c < 8; ++c) {
        const float* gc = sb + (size_t)(8 + c) * G3;
        buf1[c * HALO_N + tid] = gc[vo0];
        buf1[c * HALO_N + 256 + tid] = gc[vo1];
        if (act2) buf1[c * HALO_N + 512 + tid] = gc[vo2];
    }
#endif

    // Packed perception features (h2 pp[j] = features 2j,2j+1; x = k*16+c).
    h2 pp[32];
    float pf0 = 0.f, pf1 = 0.f, pf2 = 0.f, pf3 = 0.f; // even-channel carry
    float amax = -3.0e38f;

#pragma unroll
    for (int g = 0; g < 2; ++g) {
        const float* bb = g ? buf1 : buf0;
        if (g) __syncthreads(); // drains buf1's loads (issued pre-stencil-g0)

#pragma unroll
        for (int c = 0; c < 8; ++c) {
            const int cg = g * 8 + c;
            const float* buf = bb + c * HALO_N;
            float P0 = 0.f, P2 = 0.f, U0 = 0.f, U2 = 0.f, V0 = 0.f, V2 = 0.f;
            float ctr = 0.f, mx = -3.0e38f;
#pragma unroll
            for (int dz = 0; dz < 3; ++dz) {
                const float gzw = (dz == 1) ? 2.f : 1.f;
#pragma unroll
                for (int dy = 0; dy < 3; ++dy) {
                    const float gyw = (dy == 1) ? 2.f : 1.f;
                    const float* r = buf + cbase + dz * 100 + dy * 10;
                    const float a0 = r[0], a1 = r[1], a2 = r[2];
                    const float rs = a0 + 2.f * a1 + a2;
                    if (dz == 0) P0 += gyw * rs;
                    if (dz == 2) P2 += gyw * rs;
                    if (dy == 0) U0 += gzw * rs;
                    if (dy == 2) U2 += gzw * rs;
                    V0 += gzw * gyw * a0;
                    V2 += gzw * gyw * a2;
                    if (dz == 1 && dy == 1) ctr = a1;
                    if (cg == 3) mx = fmaxf(mx, fmaxf(fmaxf(a0, a1), a2));
                }
            }
            if (cg == 3) amax = mx;

            const float f0 = ctr;
            const float f1 = (P0 - P2) * 0.0625f;
            const float f2 = (U0 - U2) * 0.0625f;
            const float f3 = (V0 - V2) * 0.0625f;

            if (cg & 1) {
                const int j = cg >> 1;
                h2 v;
                v.x = (_Float16)pf0; v.y = (_Float16)f0; pp[j]      = v;
                v.x = (_Float16)pf1; v.y = (_Float16)f1; pp[8 + j]  = v;
                v.x = (_Float16)pf2; v.y = (_Float16)f2; pp[16 + j] = v;
                v.x = (_Float16)pf3; v.y = (_Float16)f3; pp[24 + j] = v;
            } else {
                pf0 = f0; pf1 = f1; pf2 = f2; pf3 = f3;
            }
        }
    }

    // All waves finished reading the buffers; X/H panels may overwrite.
    __syncthreads();

    const float pre = (amax > 0.1f) ? 1.f : 0.f; // own voxel

    // =================== MFMA MLP (wave-private) ===================
    const int lane = tid & 63;
    const int w    = tid >> 6;       // wave = z-slice
    const int l15  = lane & 15;
    const int lg   = lane >> 4;      // lane group 0..3
    char* xw = smem + w * XWAVE;

    // --- write X-panel: row v = lane (this thread's voxel), 64 f16 ---
#pragma unroll
    for (int q = 0; q < 8; ++q) {
        uint4 t;
        t.x = __builtin_bit_cast(unsigned, pp[4 * q]);
        t.y = __builtin_bit_cast(unsigned, pp[4 * q + 1]);
        t.z = __builtin_bit_cast(unsigned, pp[4 * q + 2]);
        t.w = __builtin_bit_cast(unsigned, pp[4 * q + 3]);
        *(uint4*)(xw + lane * XROW + q * 16) = t;
    }

    // --- load B1 fragments (X^T): B[k][v], lane: k=lg*8+j, v=nt*16+l15 ---
    f16x8 bfr[8]; // [kt*4 + nt]
#pragma unroll
    for (int kt = 0; kt < 2; ++kt)
#pragma unroll
        for (int nt = 0; nt < 4; ++nt)
            bfr[kt * 4 + nt] = *(const f16x8*)(xw + (nt * 16 + l15) * XROW + kt * 64 + lg * 16);

    // --- park the identity features (this thread's s0, f16) in the dead
    //     zone of the wave panel (bytes 6144..8192; H/transpose stay <5120).
    //     After this, pp[0..7] are DEAD -> GEMM live set fits the 64 tier.
    {
        uint4 ia, ib;
        ia.x = __builtin_bit_cast(unsigned, pp[0]);
        ia.y = __builtin_bit_cast(unsigned, pp[1]);
        ia.z = __builtin_bit_cast(unsigned, pp[2]);
        ia.w = __builtin_bit_cast(unsigned, pp[3]);
        ib.x = __builtin_bit_cast(unsigned, pp[4]);
        ib.y = __builtin_bit_cast(unsigned, pp[5]);
        ib.z = __builtin_bit_cast(unsigned, pp[6]);
        ib.w = __builtin_bit_cast(unsigned, pp[7]);
        *(uint4*)(xw + PARK0 + lane * 16) = ia;
        *(uint4*)(xw + PARK1 + lane * 16) = ib;
    }

    const f16x8* a1 = ((const f16x8*)a1p) + lane;
    const f16x8* a2 = ((const f16x8*)a2p) + lane;

    f32x4 acc2[4];
#pragma unroll
    for (int nt = 0; nt < 4; ++nt) acc2[nt] = (f32x4){0.f, 0.f, 0.f, 0.f};

    // --- interleaved GEMM1/GEMM2 per 32-row hidden block ---
#pragma unroll 1
    for (int kt2 = 0; kt2 < 3; ++kt2) {
#pragma unroll
        for (int mtsub = 0; mtsub < 2; ++mtsub) {
            const int mt = kt2 * 2 + mtsub;
            const f16x8 a_0 = a1[(mt * 2 + 0) * 64];
            const f16x8 a_1 = a1[(mt * 2 + 1) * 64];
            const f32x4 bias = *(const f32x4*)(b1 + mt * 16 + lg * 4);
#pragma unroll
            for (int nt = 0; nt < 4; ++nt) {
                f32x4 acc = (f32x4){0.f, 0.f, 0.f, 0.f};
                acc = mfma16(a_0, bfr[nt],     acc);
                acc = mfma16(a_1, bfr[4 + nt], acc);
                f16x4 hv;
                hv[0] = (_Float16)fmaxf(acc[0] + bias[0], 0.f);
                hv[1] = (_Float16)fmaxf(acc[1] + bias[1], 0.f);
                hv[2] = (_Float16)fmaxf(acc[2] + bias[2], 0.f);
                hv[3] = (_Float16)fmaxf(acc[3] + bias[3], 0.f);
                *(f16x4*)(xw + (nt * 16 + l15) * HROW + mtsub * 32 + lg * 8) = hv;
            }
        }
        const f16x8 a2f = a2[kt2 * 64];
#pragma unroll
        for (int nt = 0; nt < 4; ++nt) {
            const f16x8 b2 = *(const f16x8*)(xw + (nt * 16 + l15) * HROW + lg * 16);
            acc2[nt] = mfma16(a2f, b2, acc2[nt]);
        }
    }

    // --- delta transpose through the (now dead) H panel: row = voxel ---
#pragma unroll
    for (int nt = 0; nt < 4; ++nt) {
        *(f32x4*)(xw + (nt * 16 + l15) * HROW + lg * 16) = acc2[nt];
    }

    // --- epilogue: own voxel, all 16 channels; s0 = parked identity (f16,
    //     numerics validated by R17/R18: absmax 0.03125) ---
    const float m = (ru < 0.5f) ? 1.f : 0.f;
    const uint4 ia = *(const uint4*)(xw + PARK0 + lane * 16);
    const uint4 ib = *(const uint4*)(xw + PARK1 + lane * 16);
    float s0v[16];
    {
        const unsigned wds[8] = {ia.x, ia.y, ia.z, ia.w, ib.x, ib.y, ib.z, ib.w};
#pragma unroll
        for (int j = 0; j < 8; ++j) {
            const h2 p = __builtin_bit_cast(h2, wds[j]);
            s0v[2 * j]     = (float)p.x;
            s0v[2 * j + 1] = (float)p.y;
        }
    }
    float* ob = out + (size_t)n * C * G3;
    float* ac = acopy + (size_t)n * G3;
#pragma unroll
    for (int q = 0; q < 4; ++q) {
        const f32x4 dv = *(const f32x4*)(xw + lane * HROW + q * 16);
#pragma unroll
        for (int r = 0; r < 4; ++r) {
            const int c = q * 4 + r;
            const float nv = fmaf(dv[r], m, s0v[c]);
            if (c == 3) ac[vofs] = nv; // UNMASKED new alpha
            ob[(size_t)c * G3 + vofs] = nv * pre;
        }
    }
}

// ---------------------------------------------------------------------------
// Pass 2 (fused): post-alive pooling on the unmasked new alpha (acopy) ->
// zero out dead voxels only. Alive voxels (overwhelming majority) touch no
// out traffic: multiplying by 1 is a no-op. Bit-exact vs out *= mask.
// ---------------------------------------------------------------------------
__global__ __launch_bounds__(256)
void nca_post(const float* __restrict__ acopy, float* __restrict__ out)
{
    const int idx = blockIdx.x * 256 + threadIdx.x; // over NBATCH*G3
    const int n = idx >> 18;
    const int v = idx & (G3 - 1);
    const int x = v & 63, y = (v >> 6) & 63, z = v >> 12;
    const float* ab = acopy + (size_t)n * G3;
    float mx = -3.0e38f;
#pragma unroll
    for (int dz = -1; dz <= 1; ++dz) {
        const int zz = min(max(z + dz, 0), G - 1);
#pragma unroll
        for (int dy = -1; dy <= 1; ++dy) {
            const int yy = min(max(y + dy, 0), G - 1);
            const int xm = max(x - 1, 0), xp = min(x + 1, G - 1);
            const float* row = ab + (size_t)zz * (G * G) + (size_t)yy * G;
            mx = fmaxf(mx, fmaxf(fmaxf(row[xm], row[x]), row[xp]));
        }
    }
    if (mx > 0.1f) return; // alive: out already holds new_state * pre
    float* ob = out + (size_t)n * C * G3 + v;
#pragma unroll
    for (int c = 0; c < C; ++c) ob[(size_t)c * G3] = 0.f;
}

extern "C" void kernel_launch(void* const* d_in, const int* in_sizes, int n_in,
                              void* d_out, int out_size, void* d_ws, size_t ws_size,
                              hipStream_t stream)
{
    const float* state  = (const float*)d_in[0];
    const float* rand_u = (const float*)d_in[1];
    const float* w1     = (const float*)d_in[2];
    const float* b1     = (const float*)d_in[3];
    const float* w2     = (const float*)d_in[4];
    float* out  = (float*)d_out;

    // Workspace: [0,12KB) a1p, [12KB,15KB) a2p, [16KB, 16KB+4MiB) acopy.
    _Float16* a1p  = (_Float16*)d_ws;
    _Float16* a2p  = (_Float16*)((char*)d_ws + 12 * 1024);
    float*    acop = (float*)((char*)d_ws + 16 * 1024);

    nca_packw <<<24, 256, 0, stream>>>(w1, w2, a1p, a2p);
    nca_update<<<NBATCH * 8 * 8 * 16, 256, 0, stream>>>(state, rand_u, a1p, b1, a2p, out, acop);
    nca_post  <<<(NBATCH * G3) / 256, 256, 0, stream>>>(acop, out);
}

// Round 20
// 111.708 us; speedup vs baseline: 2.1603x; 1.0766x over previous
//
#include <hip/hip_runtime.h>

constexpr int G = 64;
constexpr int C = 16;
constexpr int NBATCH = 4;
constexpr int HID = 96;
constexpr int G3 = G * G * G; // 262144 = 2^18

typedef _Float16 h2    __attribute__((ext_vector_type(2)));
typedef _Float16 f16x4 __attribute__((ext_vector_type(4)));
typedef _Float16 f16x8 __attribute__((ext_vector_type(8)));
typedef float    f32x4 __attribute__((ext_vector_type(4)));

__device__ __forceinline__ f32x4 mfma16(f16x8 a, f16x8 b, f32x4 c) {
    return __builtin_amdgcn_mfma_f32_16x16x32_f16(a, b, c, 0, 0, 0);
}

#if __has_builtin(__builtin_amdgcn_global_load_lds)
#define HAS_GLL 1
__device__ __forceinline__ void gload_lds(const float* g, float* l) {
    __builtin_amdgcn_global_load_lds(
        (const __attribute__((address_space(1))) void*)g,
        (__attribute__((address_space(3))) void*)l, 4, 0, 0);
}
#else
#define HAS_GLL 0
#endif

// ---------------------------------------------------------------------------
// Pass 0: pack W1 (96x64) and W2 (16x96) into MFMA A-fragment order (f16).
// A-frag for mfma_f32_16x16x32_f16: lane l holds A[row = l%16][k = (l/16)*8+j],
// j=0..7 (16B contiguous per lane). (Layout verified by R11: absmax 0.03125.)
// ---------------------------------------------------------------------------
__global__ __launch_bounds__(256)
void nca_packw(const float* __restrict__ w1, const float* __restrict__ w2,
               _Float16* __restrict__ a1p, _Float16* __restrict__ a2p)
{
    const int i = blockIdx.x * 256 + threadIdx.x; // 0..6143
    {
        const int j = i & 7, lane = (i >> 3) & 63, f = i >> 9; // f = mt*2+kt
        const int mt = f >> 1, kt = f & 1;
        const int y = mt * 16 + (lane & 15);
        const int x = kt * 32 + ((lane >> 4) << 3) + j;
        a1p[i] = (_Float16)w1[y * 64 + x];
    }
    if (i < 3 * 512) {
        const int j = i & 7, lane = (i >> 3) & 63, kt2 = i >> 9;
        const int c = lane & 15;
        const int y = kt2 * 32 + ((lane >> 4) << 3) + j;
        a2p[i] = (_Float16)w2[c * HID + y];
    }
}

// ---------------------------------------------------------------------------
// Pass 1: perception + MFMA MLP + pre-alive fold-in.
//
// R20 = R16 (the proven best: 84 VGPR, (256,3), ctrf in regs, zero spill,
// 110.2 us) + bank-conflict elimination. R17-R19's three attempts at the
// 64-VGPR tier all spilled (the voxel-major epilogue's live set is ~70) --
// abandoned. The new lever: SQ_LDS_BANK_CONFLICT 1.7e7 ~= 2075 cyc/wave:
//  (a) X-panel XROW=144 B: lane stride = 9 quads == 1 (mod 8) -> lanes with
//      equal lane%8 share a bank-quad -> 8-way conflicts on all 16 X-panel
//      b128 ops. Fix: XROW=128 + XOR swizzle (q*16)^((row&7)<<4) applied to
//      BOTH the write and the bfr read (T2; wave-private, same involution).
//  (b) stencil linear 10/100 layout: 64-lane window {10*ly+lx} mod 32 is
//      2-3-way. Padded SY=12/SZ=120 makes it exactly 2 lanes/bank = free
//      (m136). gload_lds feeds the padded layout via 720 slots/channel;
//      pad slots (lx>=10) do dummy clamped loads (never read).
// LDS 2 x 23040 = 46080 B -> 3 blocks/CU unchanged (138 KB < 160 KB).
// Invariant: WRITE_SIZE 69632 KB (zero spill).
// ---------------------------------------------------------------------------
constexpr int SYp = 12;             // padded row stride (floats)
constexpr int SZp = 120;            // padded plane stride (floats)
constexpr int SLOTS = 6 * SZp;      // 720 slots per channel (6 z-planes)
constexpr int BUF_F = 8 * SLOTS;    // 5760 floats per 8-channel buffer
constexpr int XROW = 128;           // X-panel row stride (bytes), swizzled
constexpr int XWAVE = 64 * XROW;    // 8192 B per wave
constexpr int HROW = 80;            // H / delta-transpose row stride (bytes)

__global__ __launch_bounds__(256, 3)
void nca_update(const float* __restrict__ state, const float* __restrict__ rand_u,
                const _Float16* __restrict__ a1p, const float* __restrict__ b1,
                const _Float16* __restrict__ a2p,
                float* __restrict__ out, float* __restrict__ acopy)
{
    // Stencil: 2 x 5760 floats = 46080 B. GEMM panels (4 x 8192 = 32768 B)
    // alias the same region after the post-stencil barrier.
    __shared__ __align__(16) char smem[2 * BUF_F * 4];
    float* buf0 = (float*)smem;
    float* buf1 = buf0 + BUF_F;

    const int tid = threadIdx.x;
    const int bid = blockIdx.x;
    const int bx = bid & 7, by = (bid >> 3) & 7, bz = (bid >> 6) & 15, n = bid >> 10;
    const int x0 = bx * 8, y0 = by * 8, z0 = bz * 4;
    const float* sb = state + (size_t)n * C * G3;

    // --- halo source offsets for padded slots (identical every channel).
    //     Slot s: lz = s/120, ly = (s%120)/12, lx = (s%120)%12.
    //     lx>=10 is a pad slot: load a clamped dummy (never read).
    int vo0, vo1, vo2;
    {
        const int j = tid;
        const int lz = j / SZp, rr = j % SZp, ly = rr / SYp, lx = min(rr % SYp, 9);
        vo0 = min(max(z0 + lz - 1, 0), G - 1) * (G * G)
            + min(max(y0 + ly - 1, 0), G - 1) * G
            + min(max(x0 + lx - 1, 0), G - 1);
    }
    {
        const int j = tid + 256;
        const int lz = j / SZp, rr = j % SZp, ly = rr / SYp, lx = min(rr % SYp, 9);
        vo1 = min(max(z0 + lz - 1, 0), G - 1) * (G * G)
            + min(max(y0 + ly - 1, 0), G - 1) * G
            + min(max(x0 + lx - 1, 0), G - 1);
    }
    const bool act2 = (tid + 512 < SLOTS); // tid < 208
    {
        const int j = min(tid + 512, SLOTS - 1);
        const int lz = j / SZp, rr = j % SZp, ly = rr / SYp, lx = min(rr % SYp, 9);
        vo2 = min(max(z0 + lz - 1, 0), G - 1) * (G * G)
            + min(max(y0 + ly - 1, 0), G - 1) * G
            + min(max(x0 + lx - 1, 0), G - 1);
    }
    const int wbase = tid & ~63; // wave-uniform LDS slot base

    // Own voxel (== lane's voxel of wave's z-slice).
    const int lxl = (tid & 7) + 1, lyl = ((tid >> 3) & 7) + 1, lzl = (tid >> 6) + 1;
    const int cbase = (lzl - 1) * SZp + (lyl - 1) * SYp + (lxl - 1);
    const size_t vofs = (size_t)(z0 + lzl - 1) * (G * G)
                      + (size_t)(y0 + lyl - 1) * G + (x0 + lxl - 1);
    const float ru = rand_u[(size_t)n * G3 + vofs]; // own rand, issued early

#if HAS_GLL
    // --- issue group 0 (ch 0-7) -> buf0, async, zero VGPR ---
#pragma unroll
    for (int c = 0; c < 8; ++c) {
        const float* gc = sb + (size_t)c * G3;
        gload_lds(gc + vo0, buf0 + c * SLOTS + wbase);
        gload_lds(gc + vo1, buf0 + c * SLOTS + 256 + wbase);
        if (act2) gload_lds(gc + vo2, buf0 + c * SLOTS + 512 + wbase);
    }
    __syncthreads(); // drains vmcnt -> buf0 complete

    // --- issue group 1 (ch 8-15) -> buf1; latency hides under stencil g0 ---
#pragma unroll
    for (int c = 0; c < 8; ++c) {
        const float* gc = sb + (size_t)(8 + c) * G3;
        gload_lds(gc + vo0, buf1 + c * SLOTS + wbase);
        gload_lds(gc + vo1, buf1 + c * SLOTS + 256 + wbase);
        if (act2) gload_lds(gc + vo2, buf1 + c * SLOTS + 512 + wbase);
    }
#else
    // Fallback: synchronous staging (correct, no overlap).
#pragma unroll
    for (int c = 0; c < 8; ++c) {
        const float* gc = sb + (size_t)c * G3;
        buf0[c * SLOTS + tid] = gc[vo0];
        buf0[c * SLOTS + 256 + tid] = gc[vo1];
        if (act2) buf0[c * SLOTS + 512 + tid] = gc[vo2];
    }
    __syncthreads();
#pragma unroll
    for (int c = 0; c < 8; ++c) {
        const float* gc = sb + (size_t)(8 + c) * G3;
        buf1[c * SLOTS + tid] = gc[vo0];
        buf1[c * SLOTS + 256 + tid] = gc[vo1];
        if (act2) buf1[c * SLOTS + 512 + tid] = gc[vo2];
    }
#endif

    // Packed perception features + exact fp32 centers (R16's proven form).
    h2 pp[32];
    float ctrf[C]; // own-voxel centers: exact s0 passthrough
    float pf0 = 0.f, pf1 = 0.f, pf2 = 0.f, pf3 = 0.f; // even-channel carry
    float amax = -3.0e38f;

#pragma unroll
    for (int g = 0; g < 2; ++g) {
        const float* bb = g ? buf1 : buf0;
        if (g) __syncthreads(); // drains buf1's loads (issued pre-stencil-g0)

#pragma unroll
        for (int c = 0; c < 8; ++c) {
            const int cg = g * 8 + c;
            const float* buf = bb + c * SLOTS;
            float P0 = 0.f, P2 = 0.f, U0 = 0.f, U2 = 0.f, V0 = 0.f, V2 = 0.f;
            float ctr = 0.f, mx = -3.0e38f;
#pragma unroll
            for (int dz = 0; dz < 3; ++dz) {
                const float gzw = (dz == 1) ? 2.f : 1.f;
#pragma unroll
                for (int dy = 0; dy < 3; ++dy) {
                    const float gyw = (dy == 1) ? 2.f : 1.f;
                    const float* r = buf + cbase + dz * SZp + dy * SYp;
                    const float a0 = r[0], a1 = r[1], a2 = r[2];
                    const float rs = a0 + 2.f * a1 + a2;
                    if (dz == 0) P0 += gyw * rs;
                    if (dz == 2) P2 += gyw * rs;
                    if (dy == 0) U0 += gzw * rs;
                    if (dy == 2) U2 += gzw * rs;
                    V0 += gzw * gyw * a0;
                    V2 += gzw * gyw * a2;
                    if (dz == 1 && dy == 1) ctr = a1;
                    if (cg == 3) mx = fmaxf(mx, fmaxf(fmaxf(a0, a1), a2));
                }
            }
            if (cg == 3) amax = mx;
            ctrf[cg] = ctr;

            const float f0 = ctr;
            const float f1 = (P0 - P2) * 0.0625f;
            const float f2 = (U0 - U2) * 0.0625f;
            const float f3 = (V0 - V2) * 0.0625f;

            if (cg & 1) {
                const int j = cg >> 1;
                h2 v;
                v.x = (_Float16)pf0; v.y = (_Float16)f0; pp[j]      = v;
                v.x = (_Float16)pf1; v.y = (_Float16)f1; pp[8 + j]  = v;
                v.x = (_Float16)pf2; v.y = (_Float16)f2; pp[16 + j] = v;
                v.x = (_Float16)pf3; v.y = (_Float16)f3; pp[24 + j] = v;
            } else {
                pf0 = f0; pf1 = f1; pf2 = f2; pf3 = f3;
            }
        }
    }

    // All waves finished reading the buffers; X/H panels may overwrite.
    __syncthreads();

    const float pre = (amax > 0.1f) ? 1.f : 0.f; // own voxel

    // =================== MFMA MLP (wave-private) ===================
    const int lane = tid & 63;
    const int w    = tid >> 6;       // wave = z-slice
    const int l15  = lane & 15;
    const int lg   = lane >> 4;      // lane group 0..3
    char* xw = smem + w * XWAVE;

    // --- write X-panel: row v = lane, 64 f16, XOR-swizzled 16B slots.
    //     XROW=128: without swizzle every row's slot q sits in quad q ->
    //     8-way; with s' = s ^ (row&7) each row permutes quads (T2).
#pragma unroll
    for (int q = 0; q < 8; ++q) {
        uint4 t;
        t.x = __builtin_bit_cast(unsigned, pp[4 * q]);
        t.y = __builtin_bit_cast(unsigned, pp[4 * q + 1]);
        t.z = __builtin_bit_cast(unsigned, pp[4 * q + 2]);
        t.w = __builtin_bit_cast(unsigned, pp[4 * q + 3]);
        *(uint4*)(xw + lane * XROW + ((q * 16) ^ ((lane & 7) << 4))) = t;
    }

    // --- load B1 fragments (X^T): B[k][v], lane: k=lg*8+j, v=nt*16+l15 ---
    f16x8 bfr[8]; // [kt*4 + nt]
#pragma unroll
    for (int kt = 0; kt < 2; ++kt)
#pragma unroll
        for (int nt = 0; nt < 4; ++nt) {
            const int v = nt * 16 + l15;
            bfr[kt * 4 + nt] = *(const f16x8*)(
                xw + v * XROW + ((kt * 64 + lg * 16) ^ ((v & 7) << 4)));
        }

    const f16x8* a1 = ((const f16x8*)a1p) + lane;
    const f16x8* a2 = ((const f16x8*)a2p) + lane;

    f32x4 acc2[4];
#pragma unroll
    for (int nt = 0; nt < 4; ++nt) acc2[nt] = (f32x4){0.f, 0.f, 0.f, 0.f};

    // --- interleaved GEMM1/GEMM2 per 32-row hidden block ---
    // (DS ops are per-wave in-order: H writes over the dead X region are
    //  safe after the bfr reads above.)
#pragma unroll 1
    for (int kt2 = 0; kt2 < 3; ++kt2) {
#pragma unroll
        for (int mtsub = 0; mtsub < 2; ++mtsub) {
            const int mt = kt2 * 2 + mtsub;
            const f16x8 a_0 = a1[(mt * 2 + 0) * 64];
            const f16x8 a_1 = a1[(mt * 2 + 1) * 64];
            const f32x4 bias = *(const f32x4*)(b1 + mt * 16 + lg * 4);
#pragma unroll
            for (int nt = 0; nt < 4; ++nt) {
                f32x4 acc = (f32x4){0.f, 0.f, 0.f, 0.f};
                acc = mfma16(a_0, bfr[nt],     acc);
                acc = mfma16(a_1, bfr[4 + nt], acc);
                f16x4 hv;
                hv[0] = (_Float16)fmaxf(acc[0] + bias[0], 0.f);
                hv[1] = (_Float16)fmaxf(acc[1] + bias[1], 0.f);
                hv[2] = (_Float16)fmaxf(acc[2] + bias[2], 0.f);
                hv[3] = (_Float16)fmaxf(acc[3] + bias[3], 0.f);
                *(f16x4*)(xw + (nt * 16 + l15) * HROW + mtsub * 32 + lg * 8) = hv;
            }
        }
        const f16x8 a2f = a2[kt2 * 64];
#pragma unroll
        for (int nt = 0; nt < 4; ++nt) {
            const f16x8 b2 = *(const f16x8*)(xw + (nt * 16 + l15) * HROW + lg * 16);
            acc2[nt] = mfma16(a2f, b2, acc2[nt]);
        }
    }

    // --- delta transpose through the (now dead) H panel: row = voxel ---
#pragma unroll
    for (int nt = 0; nt < 4; ++nt) {
        *(f32x4*)(xw + (nt * 16 + l15) * HROW + lg * 16) = acc2[nt];
    }

    // --- epilogue: own voxel, all 16 channels; s0 = ctrf (exact fp32) ---
    const float m = (ru < 0.5f) ? 1.f : 0.f;
    float* ob = out + (size_t)n * C * G3;
    float* ac = acopy + (size_t)n * G3;
#pragma unroll
    for (int q = 0; q < 4; ++q) {
        const f32x4 dv = *(const f32x4*)(xw + lane * HROW + q * 16);
#pragma unroll
        for (int r = 0; r < 4; ++r) {
            const int c = q * 4 + r;
            const float nv = fmaf(dv[r], m, ctrf[c]);
            if (c == 3) ac[vofs] = nv; // UNMASKED new alpha
            ob[(size_t)c * G3 + vofs] = nv * pre;
        }
    }
}

// ---------------------------------------------------------------------------
// Pass 2 (fused): post-alive pooling on the unmasked new alpha (acopy) ->
// zero out dead voxels only. Alive voxels (overwhelming majority) touch no
// out traffic: multiplying by 1 is a no-op. Bit-exact vs out *= mask.
// ---------------------------------------------------------------------------
__global__ __launch_bounds__(256)
void nca_post(const float* __restrict__ acopy, float* __restrict__ out)
{
    const int idx = blockIdx.x * 256 + threadIdx.x; // over NBATCH*G3
    const int n = idx >> 18;
    const int v = idx & (G3 - 1);
    const int x = v & 63, y = (v >> 6) & 63, z = v >> 12;
    const float* ab = acopy + (size_t)n * G3;
    float mx = -3.0e38f;
#pragma unroll
    for (int dz = -1; dz <= 1; ++dz) {
        const int zz = min(max(z + dz, 0), G - 1);
#pragma unroll
        for (int dy = -1; dy <= 1; ++dy) {
            const int yy = min(max(y + dy, 0), G - 1);
            const int xm = max(x - 1, 0), xp = min(x + 1, G - 1);
            const float* row = ab + (size_t)zz * (G * G) + (size_t)yy * G;
            mx = fmaxf(mx, fmaxf(fmaxf(row[xm], row[x]), row[xp]));
        }
    }
    if (mx > 0.1f) return; // alive: out already holds new_state * pre
    float* ob = out + (size_t)n * C * G3 + v;
#pragma unroll
    for (int c = 0; c < C; ++c) ob[(size_t)c * G3] = 0.f;
}

extern "C" void kernel_launch(void* const* d_in, const int* in_sizes, int n_in,
                              void* d_out, int out_size, void* d_ws, size_t ws_size,
                              hipStream_t stream)
{
    const float* state  = (const float*)d_in[0];
    const float* rand_u = (const float*)d_in[1];
    const float* w1     = (const float*)d_in[2];
    const float* b1     = (const float*)d_in[3];
    const float* w2     = (const float*)d_in[4];
    float* out  = (float*)d_out;

    // Workspace: [0,12KB) a1p, [12KB,15KB) a2p, [16KB, 16KB+4MiB) acopy.
    _Float16* a1p  = (_Float16*)d_ws;
    _Float16* a2p  = (_Float16*)((char*)d_ws + 12 * 1024);
    float*    acop = (float*)((char*)d_ws + 16 * 1024);

    nca_packw <<<24, 256, 0, stream>>>(w1, w2, a1p, a2p);
    nca_update<<<NBATCH * 8 * 8 * 16, 256, 0, stream>>>(state, rand_u, a1p, b1, a2p, out, acop);
    nca_post  <<<(NBATCH * G3) / 256, 256, 0, stream>>>(acop, out);
}